// Round 8
// baseline (7321.735 us; speedup 1.0000x reference)
//
#include <hip/hip_runtime.h>
#include <hip/hip_bf16.h>
#include <math.h>

#define Bd 128
#define Sd 256
#define Ad 8
#define Ed 300
#define Hd 300
#define EP 320
#define Pd 3

typedef __attribute__((ext_vector_type(8))) short bfrag;   // 8 bf16 (4 VGPRs)
typedef __attribute__((ext_vector_type(4))) float f32x4;   // MFMA acc

// ---- workspace layout (bytes) ----
#define OFF_LENS   0u           // int[128*4]
#define OFF_VA     8192u        // float[128*320]
#define OFF_VS     172032u      // float[128*320]
#define OFF_U      335872u      // float[128*320]
#define OFF_ATTN   499712u      // float[2*128*256]
#define OFF_ALPHA  761856u      // float[128*256]
#define OFF_C      892928u      // float[128*256]
#define OFF_PART   1024000u     // float[2 side][8 bg][4 wave][16 row][256 t] = 16.78MB
#define OFF_WF     17801216u    // ushort[2 side][2 mat][3 g][20 ut][10 kt][64 lane][8]
#define OFF_W1B    20258816u    // ushort[320*320]
#define OFF_XF     20463616u    // ushort[2 side][256 t][8 bt][10 kt][64 lane][8] = 41.94MB
#define OFF_MEMW   20463616u    // shared with XF: XF dead after k_gru, memw written after
#define WS_NEEDED  62406656u

__device__ __forceinline__ unsigned short f2bf(float f) {
    __hip_bfloat16 h = __float2bfloat16(f);
    return *reinterpret_cast<unsigned short*>(&h);
}
__device__ __forceinline__ float bf2f(unsigned short u) {
    __hip_bfloat16 h = *reinterpret_cast<__hip_bfloat16*>(&u);
    return __bfloat162float(h);
}
__device__ __forceinline__ float sigm(float x) {
    return __builtin_amdgcn_rcpf(1.f + __expf(-x));
}
__device__ __forceinline__ float fast_tanh(float x) {
    x = fminf(fmaxf(x, -15.f), 15.f);
    float e = __expf(2.f * x);
    return (e - 1.f) * __builtin_amdgcn_rcpf(e + 1.f);
}

// ---------------- lengths ----------------
__global__ void k_lengths(const int* __restrict__ text, const int* __restrict__ aspect,
                          const int* __restrict__ xl, int* __restrict__ lens) {
    int b = blockIdx.x;
    __shared__ int red[3];
    if (threadIdx.x < 3) red[threadIdx.x] = 0;
    __syncthreads();
    int t = threadIdx.x;
    if (t < Sd) {
        if (text[b*Sd + t] != 0) atomicAdd(&red[0], 1);
        if (xl[b*Sd + t]  != 0) atomicAdd(&red[2], 1);
    }
    if (t < Ad) { if (aspect[b*Ad + t] != 0) atomicAdd(&red[1], 1); }
    __syncthreads();
    if (t < 3) lens[b*4 + t] = red[t];
}

// ---------------- v_a ----------------
__global__ void k_va(const float* __restrict__ embed, const int* __restrict__ aspect,
                     const int* __restrict__ lens, float* __restrict__ va) {
    int b = blockIdx.x;
    __shared__ int aidx[Ad];
    if (threadIdx.x < Ad) aidx[threadIdx.x] = aspect[b*Ad + threadIdx.x];
    __syncthreads();
    float inv = 1.0f / (float)lens[b*4+1];
    for (int e = threadIdx.x; e < EP; e += blockDim.x) {
        float s = 0.f;
        if (e < Ed) {
            for (int a = 0; a < Ad; ++a) s += embed[(size_t)aidx[a]*Ed + e];
        }
        va[b*EP + e] = s * inv;
    }
}

// ---------------- x embeddings, fragment-major: XF[side][t][bt][kt][lane][8] ----------------
__global__ void k_xf(const float* __restrict__ embed, const int* __restrict__ xl,
                     const int* __restrict__ xr, unsigned short* __restrict__ XF) {
    int side = blockIdx.x >> 8;
    int t = blockIdx.x & 255;
    const int* xs = side ? xr : xl;
    __shared__ int rows_s[Bd];
    if (threadIdx.x < Bd) rows_s[threadIdx.x] = xs[threadIdx.x*Sd + t];
    __syncthreads();
    unsigned short* dst = XF + ((size_t)(side*Sd + t))*40960;
    for (int idx = threadIdx.x; idx < 40960; idx += 256) {
        int bt = idx / 5120;
        int r1 = idx - bt*5120;
        int kt = r1 / 512;
        int r2 = r1 - kt*512;
        int lane = r2 >> 3, j = r2 & 7;
        int b = bt*16 + (lane & 15);
        int kk = kt*32 + (lane >> 4)*8 + j;
        float v = (kk < Ed) ? embed[(size_t)rows_s[b]*Ed + kk] : 0.f;
        dst[idx] = f2bf(v);
    }
}

// ---------------- GRU weights, fragment-major: WF[side][mat][g][ut][kt][lane][8] ----------------
__global__ void k_wfrag(const float* __restrict__ wih_l, const float* __restrict__ whh_l,
                        const float* __restrict__ wih_r, const float* __restrict__ whh_r,
                        unsigned short* __restrict__ WF) {
    int bid = blockIdx.x;              // ((side*2+mat)*3+g)*20+ut
    int side = bid / 120;
    int r = bid - side*120;
    int mat = r / 60; r -= mat*60;
    int g = r / 20;
    int ut = r - g*20;
    const float* W = mat ? (side ? whh_r : whh_l) : (side ? wih_r : wih_l);
    unsigned short* dst = WF + (size_t)bid*5120;
    for (int idx = threadIdx.x; idx < 5120; idx += 256) {
        int kt = idx / 512;
        int r2 = idx - kt*512;
        int lane = r2 >> 3, j = r2 & 7;
        int unit = ut*16 + (lane & 15);
        int kk = kt*32 + (lane >> 4)*8 + j;
        float v = (unit < Hd && kk < Ed) ? W[(size_t)(g*Hd + unit)*Ed + kk] : 0.f;
        dst[idx] = f2bf(v);
    }
}

// ---------------- w1 mem-part -> bf16 padded [320][320] ----------------
__global__ void k_w1conv(const float* __restrict__ w1, unsigned short* __restrict__ w1b) {
    int idx = blockIdx.x*256 + threadIdx.x;
    if (idx >= EP*EP) return;
    int e = idx / EP, k = idx - e*EP;
    float v = (e < Ed && k < Ed) ? w1[(size_t)e*900 + k] : 0.f;
    w1b[idx] = f2bf(v);
}

// ---------------- GRU v7: batch-split, sync-free ----------------
// 16 blocks: side = bid&1, batch group bg = bid>>1 (16 rows each).
// Block computes ALL 960 (padded) gate rows for its 16 batch rows; h lives in
// LDS ping-pong, weights streamed L2->regs as MFMA fragments every step
// (2.4MB both sides - L2-resident; side-pinned via bid&1 = XCD parity).
// No inter-block communication at all. One __syncthreads per step.
__global__ __launch_bounds__(256, 1) void k_gru(
        const unsigned short* __restrict__ WF,
        const unsigned short* __restrict__ XF,
        const float* __restrict__ bih_l, const float* __restrict__ bhh_l,
        const float* __restrict__ bih_r, const float* __restrict__ bhh_r,
        const float* __restrict__ wml, const float* __restrict__ wmr,
        float* __restrict__ part) {
    int side = blockIdx.x & 1;
    int bg   = blockIdx.x >> 1;        // 0..7
    int tid = threadIdx.x;
    int wave = tid >> 6, lane = tid & 63, ul = lane & 15, lq = lane >> 4;
    const float* bih = side ? bih_r : bih_l;
    const float* bhh = side ? bhh_r : bhh_l;
    const float* wmv = side ? wmr : wml;

    __shared__ __align__(16) unsigned short h_s[2][16][328];
    __shared__ float brz[2][320];
    __shared__ float bni[320], bnh[320], wml_sh[320];

    for (int i = tid; i < (int)(sizeof(h_s)/8); i += 256)
        ((unsigned long long*)h_s)[i] = 0ull;
    for (int u = tid; u < 320; u += 256) {
        float b0=0.f, b1=0.f, b2=0.f, b3=0.f, wv=0.f;
        if (u < Hd) {
            b0 = bih[u] + bhh[u];
            b1 = bih[Hd+u] + bhh[Hd+u];
            b2 = bih[2*Hd+u];
            b3 = bhh[2*Hd+u];
            wv = wmv[u];
        }
        brz[0][u]=b0; brz[1][u]=b1; bni[u]=b2; bnh[u]=b3; wml_sh[u]=wv;
    }
    __syncthreads();

    const unsigned short* WI = WF + (size_t)(side*2+0)*3*20*10*512;
    const unsigned short* WH = WF + (size_t)(side*2+1)*3*20*10*512;

    bfrag xcur[10];
    {
        const unsigned short* xp = XF + ((size_t)(side*Sd+0)*8 + bg)*5120 + lane*8;
        #pragma unroll
        for (int kt = 0; kt < 10; ++kt)
            xcur[kt] = *(const bfrag*)(xp + kt*512);
    }

    float hreg[5][4] = {};
    const f32x4 zero4 = {0.f,0.f,0.f,0.f};
    int par = 0;

    #pragma unroll 1
    for (int t = 0; t < Sd; ++t) {
        f32x4 arz[5][2], ani[5], anh[5];
        #pragma unroll
        for (int j = 0; j < 5; ++j) {
            arz[j][0]=zero4; arz[j][1]=zero4; ani[j]=zero4; anh[j]=zero4;
        }

        // ---- gi: x_t @ wih^T (all 3 gates, wave's 5 u-tiles) ----
        #pragma unroll
        for (int j = 0; j < 5; ++j) {
            int ut = wave + 4*j;
            #pragma unroll
            for (int g = 0; g < 3; ++g) {
                const unsigned short* wp = WI + (size_t)(g*20+ut)*5120 + lane*8;
                bfrag wf[10];
                #pragma unroll
                for (int kt = 0; kt < 10; ++kt)
                    wf[kt] = *(const bfrag*)(wp + kt*512);
                #pragma unroll
                for (int kt = 0; kt < 10; ++kt) {
                    if (g == 0)
                        arz[j][0] = __builtin_amdgcn_mfma_f32_16x16x32_bf16(xcur[kt], wf[kt], arz[j][0], 0,0,0);
                    else if (g == 1)
                        arz[j][1] = __builtin_amdgcn_mfma_f32_16x16x32_bf16(xcur[kt], wf[kt], arz[j][1], 0,0,0);
                    else
                        ani[j]    = __builtin_amdgcn_mfma_f32_16x16x32_bf16(xcur[kt], wf[kt], ani[j], 0,0,0);
                }
            }
        }

        // ---- x prefetch for t+1 (overlaps gh phase) ----
        {
            int tn = (t+1 < Sd) ? t+1 : Sd-1;
            const unsigned short* xp = XF + ((size_t)(side*Sd+tn)*8 + bg)*5120 + lane*8;
            #pragma unroll
            for (int kt = 0; kt < 10; ++kt)
                xcur[kt] = *(const bfrag*)(xp + kt*512);
        }

        // ---- h fragments from LDS ----
        bfrag hf[10];
        #pragma unroll
        for (int kt = 0; kt < 10; ++kt)
            hf[kt] = *(const bfrag*)(&h_s[par][ul][kt*32 + lq*8]);

        // ---- gh: h @ whh^T ----
        #pragma unroll
        for (int j = 0; j < 5; ++j) {
            int ut = wave + 4*j;
            #pragma unroll
            for (int g = 0; g < 3; ++g) {
                const unsigned short* wp = WH + (size_t)(g*20+ut)*5120 + lane*8;
                bfrag wf[10];
                #pragma unroll
                for (int kt = 0; kt < 10; ++kt)
                    wf[kt] = *(const bfrag*)(wp + kt*512);
                #pragma unroll
                for (int kt = 0; kt < 10; ++kt) {
                    if (g == 0)
                        arz[j][0] = __builtin_amdgcn_mfma_f32_16x16x32_bf16(hf[kt], wf[kt], arz[j][0], 0,0,0);
                    else if (g == 1)
                        arz[j][1] = __builtin_amdgcn_mfma_f32_16x16x32_bf16(hf[kt], wf[kt], arz[j][1], 0,0,0);
                    else
                        anh[j]    = __builtin_amdgcn_mfma_f32_16x16x32_bf16(hf[kt], wf[kt], anh[j], 0,0,0);
                }
            }
        }

        // ---- epilogue: gates, h update (fp32 in regs), h -> LDS bf16 ----
        #pragma unroll
        for (int j = 0; j < 5; ++j) {
            int unit = (wave + 4*j)*16 + ul;
            #pragma unroll
            for (int i = 0; i < 4; ++i) {
                float r = sigm(arz[j][0][i] + brz[0][unit]);
                float z = sigm(arz[j][1][i] + brz[1][unit]);
                float nn = fast_tanh(ani[j][i] + bni[unit] + r*(anh[j][i] + bnh[unit]));
                float hv = (1.f - z)*nn + z*hreg[j][i];
                hreg[j][i] = hv;
                h_s[par^1][lq*4+i][unit] = f2bf(hv);
            }
        }

        // ---- attn partials: dot over this wave's 80 units, reduce over ul ----
        #pragma unroll
        for (int i = 0; i < 4; ++i) {
            float pv = 0.f;
            #pragma unroll
            for (int j = 0; j < 5; ++j)
                pv += hreg[j][i] * wml_sh[(wave+4*j)*16 + ul];
            pv += __shfl_xor(pv, 1, 64);
            pv += __shfl_xor(pv, 2, 64);
            pv += __shfl_xor(pv, 4, 64);
            pv += __shfl_xor(pv, 8, 64);
            if (ul == 0)
                part[(((size_t)(side*8+bg)*4 + wave)*16 + lq*4+i)*Sd + t] = pv;
        }

        __syncthreads();
        par ^= 1;
    }
}

// ---------------- reduce attn partials (4 waves) ----------------
__global__ void k_attn(const float* __restrict__ part, const float* __restrict__ bml,
                       const float* __restrict__ bmr, float* __restrict__ attn) {
    int side = blockIdx.x >> 7;
    int b = blockIdx.x & 127;
    int bg = b >> 4, r = b & 15;
    int t = threadIdx.x;
    float s = 0.f;
    for (int w = 0; w < 4; ++w)
        s += part[(((size_t)(side*8+bg)*4 + w)*16 + r)*Sd + t];
    float bias = side ? bmr[0] : bml[0];
    attn[(size_t)(side*Bd + b)*Sd + t] = sigm(s + bias) + 0.5f;
}

// ---------------- position weights + weighted memory + v_s ----------------
__global__ void k_wmem(const float* __restrict__ embed, const int* __restrict__ text,
                       const float* __restrict__ attn, const int* __restrict__ lens,
                       unsigned short* __restrict__ memw, float* __restrict__ vs) {
    int b = blockIdx.x;
    __shared__ float w_sh[Sd];
    __shared__ int text_s[Sd];
    int memlen = lens[b*4+0], asplen = lens[b*4+1], leftlen = lens[b*4+2];
    int a_start = leftlen - asplen, a_end = leftlen;
    const float* attl = attn + (size_t)b*Sd;
    const float* attr = attn + (size_t)(Bd + b)*Sd;
    if (threadIdx.x < Sd) {
        int i = threadIdx.x;
        int irr = a_end - 1 - i; irr = irr < 0 ? 0 : (irr > Sd-1 ? Sd-1 : irr);
        int ils = i - a_start;   ils = ils < 0 ? 0 : (ils > Sd-1 ? Sd-1 : ils);
        float arr_ = attr[irr], als = attl[ils];
        float w = (i < a_start) ? arr_ : ((i < a_end) ? 0.5f*(arr_+als) : als);
        if (i >= memlen) w = 1.0f;
        w_sh[i] = w;
        text_s[i] = text[b*Sd + i];
    }
    __syncthreads();
    int e = threadIdx.x;
    float acc = 0.f;
    float invm = 1.0f/(float)lens[b*4+0];
    for (int s = 0; s < Sd; ++s) {
        float v = (e < Ed) ? embed[(size_t)text_s[s]*Ed + e] : 0.f;
        float mw = v * w_sh[s];
        memw[((size_t)b*Sd + s)*EP + e] = f2bf(mw);
        acc += mw;
    }
    vs[b*EP + e] = acc * invm;
}

// ---------------- per-batch u = b1 + va@W1a^T + vs@W1s^T ----------------
__global__ void k_u(const float* __restrict__ w1, const float* __restrict__ b1,
                    const float* __restrict__ va, const float* __restrict__ vs,
                    float* __restrict__ u) {
    int b = blockIdx.x;
    __shared__ float va_s[Ed], vs_s[Ed];
    for (int k = threadIdx.x; k < Ed; k += blockDim.x) {
        va_s[k] = va[b*EP+k];
        vs_s[k] = vs[b*EP+k];
    }
    __syncthreads();
    int e = threadIdx.x;
    if (e >= EP) return;
    float acc = 0.f;
    if (e < Ed) {
        acc = b1[e];
        const float* r = w1 + (size_t)e*900;
        for (int k = 0; k < Ed; ++k) acc += va_s[k]*r[300+k];
        for (int k = 0; k < Ed; ++k) acc += vs_s[k]*r[600+k];
    }
    u[b*EP + e] = acc;
}

// ---------------- c[b,s] = w2 . tanh(memw@W1m^T + u)  (MFMA) ----------------
__global__ __launch_bounds__(256) void k_c(const unsigned short* __restrict__ memw,
                   const unsigned short* __restrict__ w1b,
                   const float* __restrict__ u, const float* __restrict__ w2,
                   float* __restrict__ cout) {
    int b = blockIdx.x >> 2;
    int s0 = (blockIdx.x & 3) * 64;
    __shared__ __align__(16) unsigned short A_s[64*328];
    __shared__ __align__(16) unsigned short Bp_s[EP*32];
    __shared__ float u_s[EP], w2_s[EP];
    for (int i = threadIdx.x; i < EP; i += 256) {
        u_s[i] = u[b*EP + i];
        w2_s[i] = (i < Ed) ? w2[i] : 0.f;
    }
    const unsigned short* Ag = memw + ((size_t)b*Sd + s0)*EP;
    for (int c8 = threadIdx.x; c8 < 64*40; c8 += 256) {
        int r = c8 / 40, kk = (c8 - r*40)*8;
        *(bfrag*)(A_s + r*328 + kk) = *(const bfrag*)(Ag + (size_t)r*EP + kk);
    }

    int wave = threadIdx.x >> 6, lane = threadIdx.x & 63;
    int ul = lane & 15, lq = lane >> 4;
    const f32x4 zero4 = {0.f,0.f,0.f,0.f};
    f32x4 acc[20];
    #pragma unroll
    for (int n = 0; n < 20; ++n) acc[n] = zero4;

    for (int kp = 0; kp < 10; ++kp) {
        __syncthreads();
        for (int c8 = threadIdx.x; c8 < EP*4; c8 += 256) {
            int e = c8 >> 2, kk = (c8 & 3)*8;
            *(bfrag*)(Bp_s + e*32 + kk) = *(const bfrag*)(w1b + (size_t)e*EP + kp*32 + kk);
        }
        __syncthreads();
        bfrag a = *(const bfrag*)(A_s + (wave*16 + ul)*328 + kp*32 + lq*8);
        #pragma unroll
        for (int n = 0; n < 20; ++n) {
            bfrag bb = *(const bfrag*)(Bp_s + (n*16 + ul)*32 + lq*8);
            acc[n] = __builtin_amdgcn_mfma_f32_16x16x32_bf16(a, bb, acc[n], 0, 0, 0);
        }
    }
    float cs[4] = {0.f,0.f,0.f,0.f};
    #pragma unroll
    for (int n = 0; n < 20; ++n) {
        int e = n*16 + ul;
        #pragma unroll
        for (int i = 0; i < 4; ++i)
            cs[i] += w2_s[e] * fast_tanh(acc[n][i] + u_s[e]);
    }
    #pragma unroll
    for (int i = 0; i < 4; ++i) {
        float v = cs[i];
        v += __shfl_xor(v, 1, 64); v += __shfl_xor(v, 2, 64);
        v += __shfl_xor(v, 4, 64); v += __shfl_xor(v, 8, 64);
        if (ul == 0) cout[(size_t)b*Sd + s0 + wave*16 + lq*4 + i] = v;
    }
}

// ---------------- softmax over s ----------------
__global__ void k_alpha(const float* __restrict__ cin, float* __restrict__ alpha) {
    int b = blockIdx.x;
    int t = threadIdx.x;
    __shared__ float buf[Sd];
    float v = cin[(size_t)b*Sd + t];
    buf[t] = v; __syncthreads();
    for (int s2 = 128; s2 > 0; s2 >>= 1) {
        if (t < s2) buf[t] = fmaxf(buf[t], buf[t+s2]);
        __syncthreads();
    }
    float mx = buf[0];
    __syncthreads();
    float ex = __expf(v - mx);
    buf[t] = ex; __syncthreads();
    for (int s2 = 128; s2 > 0; s2 >>= 1) {
        if (t < s2) buf[t] += buf[t+s2];
        __syncthreads();
    }
    alpha[(size_t)b*Sd + t] = ex / buf[0];
}

// ---------------- v_ts, v_ns, v_ms, logits, softmax ----------------
__global__ void k_final(const unsigned short* __restrict__ memw, const float* __restrict__ alpha,
                        const float* __restrict__ vs, const float* __restrict__ wm,
                        const float* __restrict__ bm, const float* __restrict__ wd,
                        const float* __restrict__ bd, float* __restrict__ out) {
    int b = blockIdx.x;
    __shared__ float al_s[Sd];
    __shared__ float vns_s[Ed];
    __shared__ float vms_s[Ed];
    __shared__ float lg_s[Pd];
    if (threadIdx.x < Sd) al_s[threadIdx.x] = alpha[(size_t)b*Sd + threadIdx.x];
    __syncthreads();
    int e = threadIdx.x;
    if (e < Ed) {
        float acc = 0.f;
        const unsigned short* mp = memw + (size_t)b*Sd*EP + e;
        for (int s = 0; s < Sd; ++s) acc += bf2f(mp[(size_t)s*EP]) * al_s[s];
        vns_s[e] = acc + vs[b*EP + e];
    }
    __syncthreads();
    if (e < Ed) {
        float acc = bm[e];
        const float* r = wm + (size_t)e*Ed;
        for (int k = 0; k < Ed; ++k) acc += vns_s[k]*r[k];
        vms_s[e] = fast_tanh(acc);
    }
    __syncthreads();
    if (e < Pd) {
        float acc = bd[e];
        const float* r = wd + (size_t)e*Ed;
        for (int k = 0; k < Ed; ++k) acc += vms_s[k]*r[k];
        lg_s[e] = acc;
    }
    __syncthreads();
    if (e < Pd) {
        float m = fmaxf(lg_s[0], fmaxf(lg_s[1], lg_s[2]));
        float den = __expf(lg_s[0]-m)+__expf(lg_s[1]-m)+__expf(lg_s[2]-m);
        out[b*Pd + e] = __expf(lg_s[e]-m)/den;
    }
}

extern "C" void kernel_launch(void* const* d_in, const int* in_sizes, int n_in,
                              void* d_out, int out_size, void* d_ws, size_t ws_size,
                              hipStream_t stream) {
    const float* embed = (const float*)d_in[0];
    const float* w1    = (const float*)d_in[1];
    const float* b1    = (const float*)d_in[2];
    const float* w2    = (const float*)d_in[3];
    const float* wm    = (const float*)d_in[4];
    const float* bm    = (const float*)d_in[5];
    const float* wd    = (const float*)d_in[6];
    const float* bd    = (const float*)d_in[7];
    const float* wih_l = (const float*)d_in[8];
    const float* whh_l = (const float*)d_in[9];
    const float* bih_l = (const float*)d_in[10];
    const float* bhh_l = (const float*)d_in[11];
    const float* wih_r = (const float*)d_in[12];
    const float* whh_r = (const float*)d_in[13];
    const float* bih_r = (const float*)d_in[14];
    const float* bhh_r = (const float*)d_in[15];
    const float* wml   = (const float*)d_in[16];
    const float* bml   = (const float*)d_in[17];
    const float* wmr   = (const float*)d_in[18];
    const float* bmr   = (const float*)d_in[19];
    const int* text    = (const int*)d_in[20];
    const int* aspect  = (const int*)d_in[21];
    const int* xl      = (const int*)d_in[22];
    const int* xr      = (const int*)d_in[23];

    if (ws_size < (size_t)WS_NEEDED) return;
    char* ws = (char*)d_ws;
    int* lens            = (int*)(ws + OFF_LENS);
    float* va            = (float*)(ws + OFF_VA);
    float* vs            = (float*)(ws + OFF_VS);
    float* u             = (float*)(ws + OFF_U);
    float* attn          = (float*)(ws + OFF_ATTN);
    float* alpha         = (float*)(ws + OFF_ALPHA);
    float* c             = (float*)(ws + OFF_C);
    float* part          = (float*)(ws + OFF_PART);
    unsigned short* WF   = (unsigned short*)(ws + OFF_WF);
    unsigned short* w1b  = (unsigned short*)(ws + OFF_W1B);
    unsigned short* XF   = (unsigned short*)(ws + OFF_XF);
    unsigned short* memw = (unsigned short*)(ws + OFF_MEMW);

    k_lengths<<<128, 256, 0, stream>>>(text, aspect, xl, lens);
    k_va     <<<128, 320, 0, stream>>>(embed, aspect, lens, va);
    k_xf     <<<512, 256, 0, stream>>>(embed, xl, xr, XF);
    k_wfrag  <<<240, 256, 0, stream>>>(wih_l, whh_l, wih_r, whh_r, WF);
    k_w1conv <<<400, 256, 0, stream>>>(w1, w1b);
    k_gru    <<<16, 256, 0, stream>>>(WF, XF, bih_l, bhh_l, bih_r, bhh_r,
                                      wml, wmr, part);
    k_attn   <<<256, 256, 0, stream>>>(part, bml, bmr, attn);
    k_wmem   <<<128, 320, 0, stream>>>(embed, text, attn, lens, memw, vs);
    k_u      <<<128, 320, 0, stream>>>(w1, b1, va, vs, u);
    k_c      <<<512, 256, 0, stream>>>(memw, w1b, u, w2, c);
    k_alpha  <<<128, 256, 0, stream>>>(c, alpha);
    k_final  <<<128, 320, 0, stream>>>(memw, alpha, vs, wm, bm, wd, bd, (float*)d_out);
}

// Round 9
// 1872.742 us; speedup vs baseline: 3.9096x; 3.9096x over previous
//
#include <hip/hip_runtime.h>
#include <hip/hip_bf16.h>
#include <math.h>

#define Bd 128
#define Sd 256
#define Ad 8
#define Ed 300
#define Hd 300
#define EP 320
#define Pd 3
#define NCB 20   // blocks per GRU side
#define ROWS 48  // 3*16 gate rows per block
#define GRID_GRU 160  // sparse launch: workers are bid%8 in {0,1}

typedef __attribute__((ext_vector_type(8))) short bfrag;   // 8 bf16 (4 VGPRs)
typedef __attribute__((ext_vector_type(4))) float f32x4;   // MFMA acc
typedef __attribute__((ext_vector_type(4))) int i32x4;     // 16B chunk

// ---- workspace layout (bytes) ----
#define OFF_LENS   0u           // int[128*4]
#define OFF_BARS   4096u        // int[2*64] : per-side flag group, slot cid
#define OFF_VA     8192u        // float[128*320]
#define OFF_VS     172032u      // float[128*320]
#define OFF_U      335872u      // float[128*320]
#define OFF_ATTN   499712u      // float[2*128*256]
#define OFF_ALPHA  761856u      // float[128*256]
#define OFF_C      892928u      // float[128*256]
#define OFF_HBUF   1024000u     // ushort[2 side][2 parity][20 cb][128 row][16 u]
#define OFF_PART   1351680u     // float[2*20*128*256]
#define OFF_W1B    6594560u     // ushort[320*320]
#define OFF_XEMB   6799360u     // ushort[2*256*128*320]
#define OFF_MEMW   48742400u    // ushort[128*256*320]
#define WS_NEEDED  69713920u

#define HREG 40960              // ushorts per (side,parity) h region

__device__ __forceinline__ unsigned short f2bf(float f) {
    __hip_bfloat16 h = __float2bfloat16(f);
    return *reinterpret_cast<unsigned short*>(&h);
}
__device__ __forceinline__ float bf2f(unsigned short u) {
    __hip_bfloat16 h = *reinterpret_cast<__hip_bfloat16*>(&u);
    return __bfloat162float(h);
}
__device__ __forceinline__ float sigm(float x) {
    return __builtin_amdgcn_rcpf(1.f + __expf(-x));
}
__device__ __forceinline__ float fast_tanh(float x) {
    x = fminf(fmaxf(x, -15.f), 15.f);
    float e = __expf(2.f * x);
    return (e - 1.f) * __builtin_amdgcn_rcpf(e + 1.f);
}

// XCD-L2-coherent 16B load/store: sc0 bypasses L1, lands in the XCD's shared
// write-back L2 (the coherence point for the side-pinned block group).
// ~200cy instead of ~900cy Infinity-Cache round trip (sc0 sc1).
__device__ __forceinline__ i32x4 l2_load16(const void* p) {
    i32x4 v;
    asm volatile("global_load_dwordx4 %0, %1, off sc0"
                 : "=v"(v) : "v"(p) : "memory");
    return v;  // NOT ready until s_waitcnt vmcnt
}
__device__ __forceinline__ void l2_store16(void* p, i32x4 v) {
    asm volatile("global_store_dwordx4 %0, %1, off sc0"
                 :: "v"(p), "v"(v) : "memory");
}

// ---------------- lengths ----------------
__global__ void k_lengths(const int* __restrict__ text, const int* __restrict__ aspect,
                          const int* __restrict__ xl, int* __restrict__ lens) {
    int b = blockIdx.x;
    __shared__ int red[3];
    if (threadIdx.x < 3) red[threadIdx.x] = 0;
    __syncthreads();
    int t = threadIdx.x;
    if (t < Sd) {
        if (text[b*Sd + t] != 0) atomicAdd(&red[0], 1);
        if (xl[b*Sd + t]  != 0) atomicAdd(&red[2], 1);
    }
    if (t < Ad) { if (aspect[b*Ad + t] != 0) atomicAdd(&red[1], 1); }
    __syncthreads();
    if (t < 3) lens[b*4 + t] = red[t];
}

// ---------------- v_a ----------------
__global__ void k_va(const float* __restrict__ embed, const int* __restrict__ aspect,
                     const int* __restrict__ lens, float* __restrict__ va) {
    int b = blockIdx.x;
    __shared__ int aidx[Ad];
    if (threadIdx.x < Ad) aidx[threadIdx.x] = aspect[b*Ad + threadIdx.x];
    __syncthreads();
    float inv = 1.0f / (float)lens[b*4+1];
    for (int e = threadIdx.x; e < EP; e += blockDim.x) {
        float s = 0.f;
        if (e < Ed) {
            for (int a = 0; a < Ad; ++a) s += embed[(size_t)aidx[a]*Ed + e];
        }
        va[b*EP + e] = s * inv;
    }
}

// ---------------- gather embeddings for GRU inputs (bf16, [side][t][b][EP]) ----------------
__global__ void k_xemb(const float* __restrict__ embed, const int* __restrict__ xl,
                       const int* __restrict__ xr, unsigned short* __restrict__ xemb) {
    int side = blockIdx.x >> 8;
    int t = blockIdx.x & 255;
    const int* xs = side ? xr : xl;
    __shared__ int rows_s[Bd];
    if (threadIdx.x < Bd) rows_s[threadIdx.x] = xs[threadIdx.x*Sd + t];
    __syncthreads();
    unsigned short* dst = xemb + ((size_t)(side*Sd + t) * Bd) * EP;
    for (int idx = threadIdx.x; idx < Bd*EP; idx += blockDim.x) {
        int b = idx / EP, k = idx - b*EP;
        float v = (k < Ed) ? embed[(size_t)rows_s[b]*Ed + k] : 0.f;
        dst[idx] = f2bf(v);
    }
}

// ---------------- w1 mem-part -> bf16 padded [320][320] ----------------
__global__ void k_w1conv(const float* __restrict__ w1, unsigned short* __restrict__ w1b) {
    int idx = blockIdx.x*256 + threadIdx.x;
    if (idx >= EP*EP) return;
    int e = idx / EP, k = idx - e*EP;
    float v = (e < Ed && k < Ed) ? w1[(size_t)e*900 + k] : 0.f;
    w1b[idx] = f2bf(v);
}

// ---------------- persistent GRU (both sides) ----------------
// v8: XCD-pinned sparse launch (R7, proven by FETCH 166->43MB) + h exchange
//     through the XCD's SHARED L2 (sc0 only) instead of Infinity Cache.
//     Flags stay agent-scope (IC) so the barrier never hangs even if the
//     block->XCD mapping assumption breaks (failure mode = absmax, not wedge).
__global__ __launch_bounds__(256, 1) void k_gru(
        const float* __restrict__ wih_l, const float* __restrict__ whh_l,
        const float* __restrict__ bih_l, const float* __restrict__ bhh_l,
        const float* __restrict__ wih_r, const float* __restrict__ whh_r,
        const float* __restrict__ bih_r, const float* __restrict__ bhh_r,
        const float* __restrict__ wml, const float* __restrict__ wmr,
        const unsigned short* __restrict__ xemb,
        unsigned short* __restrict__ hbuf,
        float* __restrict__ part, int* __restrict__ bars) {
    int lane8 = blockIdx.x & 7;
    if (lane8 > 1) return;            // non-worker XCD lanes exit
    int side = lane8;
    int cid  = blockIdx.x >> 3;       // 0..19
    int u0 = cid * 16;
    int tid = threadIdx.x;
    const float* wih = side ? wih_r : wih_l;
    const float* whh = side ? whh_r : whh_l;
    const float* bih = side ? bih_r : bih_l;
    const float* bhh = side ? bhh_r : bhh_l;
    const float* wmv = side ? wmr : wml;

    __shared__ __align__(16) unsigned short wih_s[ROWS*328];
    __shared__ __align__(16) unsigned short whh_s[ROWS*328];
    __shared__ __align__(16) unsigned short h_s[HREG];        // [20 cb][128 row][16 u]
    __shared__ __align__(16) unsigned short hn_s[Bd*16];      // [128 row][16 u]
    __shared__ float bih_sh[ROWS], bhh_sh[ROWS], wml_sh[16];

    for (int idx = tid; idx < ROWS*328; idx += 256) {
        int lr = idx / 328, k = idx - lr*328;
        int g = lr >> 4, ulw = lr & 15, u = u0 + ulw;
        float vi = 0.f, vh = 0.f;
        if (u < Hd && k < Ed) {
            int grow = g*Hd + u;
            vi = wih[(size_t)grow*Ed + k];
            vh = whh[(size_t)grow*Hd + k];
        }
        wih_s[idx] = f2bf(vi);
        whh_s[idx] = f2bf(vh);
    }
    if (tid < ROWS) {
        int g = tid >> 4, ulw = tid & 15, u = u0 + ulw;
        bih_sh[tid] = (u < Hd) ? bih[g*Hd + u] : 0.f;
        bhh_sh[tid] = (u < Hd) ? bhh[g*Hd + u] : 0.f;
    }
    if (tid < 16) {
        int u = u0 + tid;
        wml_sh[tid] = (u < Hd) ? wmv[u] : 0.f;
    }
    __syncthreads();

    int wave = tid >> 6;
    int lane = tid & 63;
    int rowbase = wave * 32;
    int ul = lane & 15;
    int lq = lane >> 4;

    float hreg[2][4] = {{0.f,0.f,0.f,0.f},{0.f,0.f,0.f,0.f}};
    unsigned short* hb = hbuf + (size_t)side * 2 * HREG;   // [parity][HREG]
    int* flg = bars + side*64;                             // flg[cid] = ready gen
    const f32x4 zero4 = {0.f, 0.f, 0.f, 0.f};
    int pollslot = (lane < NCB) ? lane : (NCB-1);

    // preload x fragments for t=0
    bfrag xcur[2][10];
    {
        const unsigned short* xg = xemb + ((size_t)(side*Sd + 0)*Bd)*EP;
        #pragma unroll
        for (int m = 0; m < 2; ++m) {
            int row = rowbase + m*16 + ul;
            #pragma unroll
            for (int kp = 0; kp < 10; ++kp)
                xcur[m][kp] = *(const bfrag*)(xg + (size_t)row*EP + kp*32 + lq*8);
        }
    }

    #pragma unroll 1
    for (int t = 0; t < Sd; ++t) {
        const unsigned short* hg = hb + (size_t)(t & 1)*HREG;
        unsigned short* hn = hb + (size_t)((t+1) & 1)*HREG + (size_t)cid*2048;

        f32x4 agi[2][3], agh[2][3];
        #pragma unroll
        for (int m = 0; m < 2; ++m)
            #pragma unroll
            for (int n = 0; n < 3; ++n) { agi[m][n] = zero4; agh[m][n] = zero4; }

        // ---- phase 1: gi = x_t @ wih^T  (pure register A-operands) ----
        #pragma unroll
        for (int kp = 0; kp < 10; ++kp) {
            int koff = kp*32 + lq*8;
            bfrag bi[3];
            #pragma unroll
            for (int n = 0; n < 3; ++n)
                bi[n] = *(const bfrag*)(wih_s + (n*16 + ul)*328 + koff);
            #pragma unroll
            for (int m = 0; m < 2; ++m)
                #pragma unroll
                for (int n = 0; n < 3; ++n)
                    agi[m][n] = __builtin_amdgcn_mfma_f32_16x16x32_bf16(xcur[m][kp], bi[n], agi[m][n], 0, 0, 0);
        }

        // ---- issue x prefetch for t+1 (completes during stage/phase2) ----
        {
            int tn = (t + 1 < Sd) ? (t + 1) : (Sd - 1);
            const unsigned short* xg = xemb + ((size_t)(side*Sd + tn)*Bd)*EP;
            #pragma unroll
            for (int m = 0; m < 2; ++m) {
                int row = rowbase + m*16 + ul;
                #pragma unroll
                for (int kp = 0; kp < 10; ++kp)
                    xcur[m][kp] = *(const bfrag*)(xg + (size_t)row*EP + kp*32 + lq*8);
            }
        }

        // ---- spin: one coalesced poll over all NCB flags, __all >= t ----
        if (t > 0) {
            while (true) {
                int v = __hip_atomic_load(flg + pollslot, __ATOMIC_RELAXED, __HIP_MEMORY_SCOPE_AGENT);
                if (__all(v >= t)) break;
                __builtin_amdgcn_s_sleep(1);
            }
        }
        asm volatile("" ::: "memory");

        // ---- stage h: 80KB linear, coalesced dwordx4 sc0 (XCD L2) -> LDS ----
        {
            i32x4 tv[20];
            #pragma unroll
            for (int j = 0; j < 20; ++j)
                tv[j] = l2_load16(hg + (size_t)(j*256 + tid)*8);
            asm volatile("s_waitcnt vmcnt(0)" ::: "memory");
            __builtin_amdgcn_sched_barrier(0);
            i32x4* hs16 = (i32x4*)h_s;
            #pragma unroll
            for (int j = 0; j < 20; ++j)
                hs16[j*256 + tid] = tv[j];
        }
        __syncthreads();

        // ---- phase 2: gh = h @ whh^T  (A-frags from LDS) ----
        #pragma unroll
        for (int kp = 0; kp < 10; ++kp) {
            int k0 = kp*32 + lq*8;
            int cb = k0 >> 4, ku = k0 & 15;
            bfrag ah[2], bh[3];
            #pragma unroll
            for (int m = 0; m < 2; ++m) {
                int row = rowbase + m*16 + ul;
                ah[m] = *(const bfrag*)(h_s + cb*2048 + row*16 + ku);
            }
            #pragma unroll
            for (int n = 0; n < 3; ++n)
                bh[n] = *(const bfrag*)(whh_s + (n*16 + ul)*328 + k0);
            #pragma unroll
            for (int m = 0; m < 2; ++m)
                #pragma unroll
                for (int n = 0; n < 3; ++n)
                    agh[m][n] = __builtin_amdgcn_mfma_f32_16x16x32_bf16(ah[m], bh[n], agh[m][n], 0, 0, 0);
        }

        // ---- epilogue: gates, h update -> hn_s ----
        #pragma unroll
        for (int m = 0; m < 2; ++m) {
            #pragma unroll
            for (int i = 0; i < 4; ++i) {
                float gr = agi[m][0][i] + bih_sh[ul]    + agh[m][0][i] + bhh_sh[ul];
                float gz = agi[m][1][i] + bih_sh[16+ul] + agh[m][1][i] + bhh_sh[16+ul];
                float gn = agi[m][2][i] + bih_sh[32+ul];
                float hn_g = agh[m][2][i] + bhh_sh[32+ul];
                float r = sigm(gr);
                float z = sigm(gz);
                float nn = fast_tanh(gn + r*hn_g);
                float hv = (1.f - z)*nn + z*hreg[m][i];
                hreg[m][i] = hv;
                int brow = rowbase + m*16 + lq*4 + i;
                hn_s[brow*16 + ul] = f2bf(hv);
            }
        }
        __syncthreads();

        // ---- coalesced h store: block's contiguous 4KB region (XCD L2) ----
        {
            const i32x4* src = (const i32x4*)hn_s;
            l2_store16(hn + (size_t)tid*8, src[tid]);
        }
        asm volatile("s_waitcnt vmcnt(0)" ::: "memory");
        __syncthreads();
        if (t < Sd-1 && tid == 0)
            __hip_atomic_store(flg + cid, t+1, __ATOMIC_RELAXED, __HIP_MEMORY_SCOPE_AGENT);

        // ---- attn partials (off critical path) ----
        #pragma unroll
        for (int m = 0; m < 2; ++m) {
            #pragma unroll
            for (int i = 0; i < 4; ++i) {
                int brow = rowbase + m*16 + lq*4 + i;
                float pv = hreg[m][i] * wml_sh[ul];
                pv += __shfl_xor(pv, 1, 64);
                pv += __shfl_xor(pv, 2, 64);
                pv += __shfl_xor(pv, 4, 64);
                pv += __shfl_xor(pv, 8, 64);
                if (ul == 0)
                    part[((size_t)(side*NCB + cid)*Bd + brow)*Sd + t] = pv;
            }
        }
    }
}

// ---------------- reduce attn partials ----------------
__global__ void k_attn(const float* __restrict__ part, const float* __restrict__ bml,
                       const float* __restrict__ bmr, float* __restrict__ attn) {
    int side = blockIdx.x >> 7;
    int b = blockIdx.x & 127;
    int t = threadIdx.x;
    float s = 0.f;
    for (int c = 0; c < NCB; ++c)
        s += part[((size_t)(side*NCB + c)*Bd + b)*Sd + t];
    float bias = side ? bmr[0] : bml[0];
    attn[(size_t)(side*Bd + b)*Sd + t] = sigm(s + bias) + 0.5f;
}

// ---------------- position weights + weighted memory + v_s ----------------
__global__ void k_wmem(const float* __restrict__ embed, const int* __restrict__ text,
                       const float* __restrict__ attn, const int* __restrict__ lens,
                       unsigned short* __restrict__ memw, float* __restrict__ vs) {
    int b = blockIdx.x;
    __shared__ float w_sh[Sd];
    __shared__ int text_s[Sd];
    int memlen = lens[b*4+0], asplen = lens[b*4+1], leftlen = lens[b*4+2];
    int a_start = leftlen - asplen, a_end = leftlen;
    const float* attl = attn + (size_t)b*Sd;
    const float* attr = attn + (size_t)(Bd + b)*Sd;
    if (threadIdx.x < Sd) {
        int i = threadIdx.x;
        int irr = a_end - 1 - i; irr = irr < 0 ? 0 : (irr > Sd-1 ? Sd-1 : irr);
        int ils = i - a_start;   ils = ils < 0 ? 0 : (ils > Sd-1 ? Sd-1 : ils);
        float arr_ = attr[irr], als = attl[ils];
        float w = (i < a_start) ? arr_ : ((i < a_end) ? 0.5f*(arr_+als) : als);
        if (i >= memlen) w = 1.0f;
        w_sh[i] = w;
        text_s[i] = text[b*Sd + i];
    }
    __syncthreads();
    int e = threadIdx.x;
    float acc = 0.f;
    float invm = 1.0f/(float)lens[b*4+0];
    for (int s = 0; s < Sd; ++s) {
        float v = (e < Ed) ? embed[(size_t)text_s[s]*Ed + e] : 0.f;
        float mw = v * w_sh[s];
        memw[((size_t)b*Sd + s)*EP + e] = f2bf(mw);
        acc += mw;
    }
    vs[b*EP + e] = acc * invm;
}

// ---------------- per-batch u = b1 + va@W1a^T + vs@W1s^T ----------------
__global__ void k_u(const float* __restrict__ w1, const float* __restrict__ b1,
                    const float* __restrict__ va, const float* __restrict__ vs,
                    float* __restrict__ u) {
    int b = blockIdx.x;
    __shared__ float va_s[Ed], vs_s[Ed];
    for (int k = threadIdx.x; k < Ed; k += blockDim.x) {
        va_s[k] = va[b*EP+k];
        vs_s[k] = vs[b*EP+k];
    }
    __syncthreads();
    int e = threadIdx.x;
    if (e >= EP) return;
    float acc = 0.f;
    if (e < Ed) {
        acc = b1[e];
        const float* r = w1 + (size_t)e*900;
        for (int k = 0; k < Ed; ++k) acc += va_s[k]*r[300+k];
        for (int k = 0; k < Ed; ++k) acc += vs_s[k]*r[600+k];
    }
    u[b*EP + e] = acc;
}

// ---------------- c[b,s] = w2 . tanh(memw@W1m^T + u)  (MFMA) ----------------
__global__ __launch_bounds__(256) void k_c(const unsigned short* __restrict__ memw,
                   const unsigned short* __restrict__ w1b,
                   const float* __restrict__ u, const float* __restrict__ w2,
                   float* __restrict__ cout) {
    int b = blockIdx.x >> 2;
    int s0 = (blockIdx.x & 3) * 64;
    __shared__ __align__(16) unsigned short A_s[64*328];
    __shared__ __align__(16) unsigned short Bp_s[EP*32];
    __shared__ float u_s[EP], w2_s[EP];
    for (int i = threadIdx.x; i < EP; i += 256) {
        u_s[i] = u[b*EP + i];
        w2_s[i] = (i < Ed) ? w2[i] : 0.f;
    }
    const unsigned short* Ag = memw + ((size_t)b*Sd + s0)*EP;
    for (int c8 = threadIdx.x; c8 < 64*40; c8 += 256) {
        int r = c8 / 40, kk = (c8 - r*40)*8;
        *(bfrag*)(A_s + r*328 + kk) = *(const bfrag*)(Ag + (size_t)r*EP + kk);
    }

    int wave = threadIdx.x >> 6, lane = threadIdx.x & 63;
    int ul = lane & 15, lq = lane >> 4;
    const f32x4 zero4 = {0.f,0.f,0.f,0.f};
    f32x4 acc[20];
    #pragma unroll
    for (int n = 0; n < 20; ++n) acc[n] = zero4;

    for (int kp = 0; kp < 10; ++kp) {
        __syncthreads();
        for (int c8 = threadIdx.x; c8 < EP*4; c8 += 256) {
            int e = c8 >> 2, kk = (c8 & 3)*8;
            *(bfrag*)(Bp_s + e*32 + kk) = *(const bfrag*)(w1b + (size_t)e*EP + kp*32 + kk);
        }
        __syncthreads();
        bfrag a = *(const bfrag*)(A_s + (wave*16 + ul)*328 + kp*32 + lq*8);
        #pragma unroll
        for (int n = 0; n < 20; ++n) {
            bfrag bb = *(const bfrag*)(Bp_s + (n*16 + ul)*32 + lq*8);
            acc[n] = __builtin_amdgcn_mfma_f32_16x16x32_bf16(a, bb, acc[n], 0, 0, 0);
        }
    }
    float cs[4] = {0.f,0.f,0.f,0.f};
    #pragma unroll
    for (int n = 0; n < 20; ++n) {
        int e = n*16 + ul;
        #pragma unroll
        for (int i = 0; i < 4; ++i)
            cs[i] += w2_s[e] * fast_tanh(acc[n][i] + u_s[e]);
    }
    #pragma unroll
    for (int i = 0; i < 4; ++i) {
        float v = cs[i];
        v += __shfl_xor(v, 1, 64); v += __shfl_xor(v, 2, 64);
        v += __shfl_xor(v, 4, 64); v += __shfl_xor(v, 8, 64);
        if (ul == 0) cout[(size_t)b*Sd + s0 + wave*16 + lq*4 + i] = v;
    }
}

// ---------------- softmax over s ----------------
__global__ void k_alpha(const float* __restrict__ cin, float* __restrict__ alpha) {
    int b = blockIdx.x;
    int t = threadIdx.x;
    __shared__ float buf[Sd];
    float v = cin[(size_t)b*Sd + t];
    buf[t] = v; __syncthreads();
    for (int s2 = 128; s2 > 0; s2 >>= 1) {
        if (t < s2) buf[t] = fmaxf(buf[t], buf[t+s2]);
        __syncthreads();
    }
    float mx = buf[0];
    __syncthreads();
    float ex = __expf(v - mx);
    buf[t] = ex; __syncthreads();
    for (int s2 = 128; s2 > 0; s2 >>= 1) {
        if (t < s2) buf[t] += buf[t+s2];
        __syncthreads();
    }
    alpha[(size_t)b*Sd + t] = ex / buf[0];
}

// ---------------- v_ts, v_ns, v_ms, logits, softmax ----------------
__global__ void k_final(const unsigned short* __restrict__ memw, const float* __restrict__ alpha,
                        const float* __restrict__ vs, const float* __restrict__ wm,
                        const float* __restrict__ bm, const float* __restrict__ wd,
                        const float* __restrict__ bd, float* __restrict__ out) {
    int b = blockIdx.x;
    __shared__ float al_s[Sd];
    __shared__ float vns_s[Ed];
    __shared__ float vms_s[Ed];
    __shared__ float lg_s[Pd];
    if (threadIdx.x < Sd) al_s[threadIdx.x] = alpha[(size_t)b*Sd + threadIdx.x];
    __syncthreads();
    int e = threadIdx.x;
    if (e < Ed) {
        float acc = 0.f;
        const unsigned short* mp = memw + (size_t)b*Sd*EP + e;
        for (int s = 0; s < Sd; ++s) acc += bf2f(mp[(size_t)s*EP]) * al_s[s];
        vns_s[e] = acc + vs[b*EP + e];
    }
    __syncthreads();
    if (e < Ed) {
        float acc = bm[e];
        const float* r = wm + (size_t)e*Ed;
        for (int k = 0; k < Ed; ++k) acc += vns_s[k]*r[k];
        vms_s[e] = fast_tanh(acc);
    }
    __syncthreads();
    if (e < Pd) {
        float acc = bd[e];
        const float* r = wd + (size_t)e*Ed;
        for (int k = 0; k < Ed; ++k) acc += vms_s[k]*r[k];
        lg_s[e] = acc;
    }
    __syncthreads();
    if (e < Pd) {
        float m = fmaxf(lg_s[0], fmaxf(lg_s[1], lg_s[2]));
        float den = __expf(lg_s[0]-m)+__expf(lg_s[1]-m)+__expf(lg_s[2]-m);
        out[b*Pd + e] = __expf(lg_s[e]-m)/den;
    }
}

extern "C" void kernel_launch(void* const* d_in, const int* in_sizes, int n_in,
                              void* d_out, int out_size, void* d_ws, size_t ws_size,
                              hipStream_t stream) {
    const float* embed = (const float*)d_in[0];
    const float* w1    = (const float*)d_in[1];
    const float* b1    = (const float*)d_in[2];
    const float* w2    = (const float*)d_in[3];
    const float* wm    = (const float*)d_in[4];
    const float* bm    = (const float*)d_in[5];
    const float* wd    = (const float*)d_in[6];
    const float* bd    = (const float*)d_in[7];
    const float* wih_l = (const float*)d_in[8];
    const float* whh_l = (const float*)d_in[9];
    const float* bih_l = (const float*)d_in[10];
    const float* bhh_l = (const float*)d_in[11];
    const float* wih_r = (const float*)d_in[12];
    const float* whh_r = (const float*)d_in[13];
    const float* bih_r = (const float*)d_in[14];
    const float* bhh_r = (const float*)d_in[15];
    const float* wml   = (const float*)d_in[16];
    const float* bml   = (const float*)d_in[17];
    const float* wmr   = (const float*)d_in[18];
    const float* bmr   = (const float*)d_in[19];
    const int* text    = (const int*)d_in[20];
    const int* aspect  = (const int*)d_in[21];
    const int* xl      = (const int*)d_in[22];
    const int* xr      = (const int*)d_in[23];

    if (ws_size < (size_t)WS_NEEDED) return;
    char* ws = (char*)d_ws;
    int* lens            = (int*)(ws + OFF_LENS);
    int* bars            = (int*)(ws + OFF_BARS);
    float* va            = (float*)(ws + OFF_VA);
    float* vs            = (float*)(ws + OFF_VS);
    float* u             = (float*)(ws + OFF_U);
    float* attn          = (float*)(ws + OFF_ATTN);
    float* alpha         = (float*)(ws + OFF_ALPHA);
    float* c             = (float*)(ws + OFF_C);
    unsigned short* hbuf = (unsigned short*)(ws + OFF_HBUF);
    float* part          = (float*)(ws + OFF_PART);
    unsigned short* w1b  = (unsigned short*)(ws + OFF_W1B);
    unsigned short* xemb = (unsigned short*)(ws + OFF_XEMB);
    unsigned short* memw = (unsigned short*)(ws + OFF_MEMW);

    hipMemsetAsync(ws + OFF_BARS, 0, 4096, stream);
    hipMemsetAsync(ws + OFF_HBUF, 0, 327680, stream);

    k_lengths<<<128, 256, 0, stream>>>(text, aspect, xl, lens);
    k_va     <<<128, 320, 0, stream>>>(embed, aspect, lens, va);
    k_xemb   <<<512, 256, 0, stream>>>(embed, xl, xr, xemb);
    k_w1conv <<<400, 256, 0, stream>>>(w1, w1b);
    k_gru    <<<GRID_GRU, 256, 0, stream>>>(wih_l, whh_l, bih_l, bhh_l,
                                            wih_r, whh_r, bih_r, bhh_r,
                                            wml, wmr, xemb, hbuf, part, bars);
    k_attn   <<<256, 256, 0, stream>>>(part, bml, bmr, attn);
    k_wmem   <<<128, 320, 0, stream>>>(embed, text, attn, lens, memw, vs);
    k_u      <<<128, 320, 0, stream>>>(w1, b1, va, vs, u);
    k_c      <<<512, 256, 0, stream>>>(memw, w1b, u, w2, c);
    k_alpha  <<<128, 256, 0, stream>>>(c, alpha);
    k_final  <<<128, 320, 0, stream>>>(memw, alpha, vs, wm, bm, wd, bd, (float*)d_out);
}